// Round 11
// baseline (247.057 us; speedup 1.0000x reference)
//
#include <hip/hip_runtime.h>
#include <hip/hip_bf16.h>

#define B_ 4
#define U_ 16
#define L_ 128
#define H_ 768
#define M_ 256
#define HID_ 150

typedef _Float16 half8 __attribute__((ext_vector_type(8)));
typedef _Float16 half4t __attribute__((ext_vector_type(4)));
typedef float floatx4 __attribute__((ext_vector_type(4)));

#define MFMA16(af, bf, acc) __builtin_amdgcn_mfma_f32_16x16x32_f16(af, bf, acc, 0, 0, 0)

// ---------------------------------------------------------------------------
// Kernel 0: fused prep (blocks 0..1539) + pool (blocks 1540..1795).
// 16x16 B-frag packing (HW-verified R6..R10): (k,n) ->
// ((k>>5)*T + (n>>4))*512 + (((n&15)|(((k>>3)&3)<<4))<<3) + (k&7).
// ---------------------------------------------------------------------------
__global__ __launch_bounds__(256) void prep_pool_kernel(
    const float* __restrict__ W1, const float* __restrict__ W2,
    const float* __restrict__ b2, const float* __restrict__ W3,
    const float* __restrict__ hidden, const int* __restrict__ sutt,
    const int* __restrict__ sstart, const int* __restrict__ send,
    _Float16* __restrict__ W1cs, _Float16* __restrict__ W2s,
    _Float16* __restrict__ W1abs, float2* __restrict__ bw,
    _Float16* __restrict__ pooledh)
{
    if (blockIdx.x >= 1540) {   // ---- pool part ----
        const int bm = (blockIdx.x - 1540) * 4 + (threadIdx.x >> 6);
        const int lane = threadIdx.x & 63;
        const int b  = bm >> 8;
        const int u  = sutt[bm];
        const int st = sstart[bm];
        const int en = send[bm];
        const float inv = 1.0f / (float)(en - st);
        const float* src = hidden + ((size_t)(b * U_ + u) * L_) * H_ + lane * 12;
        float4 s[3];
        #pragma unroll
        for (int q = 0; q < 3; ++q) s[q] = make_float4(0.f, 0.f, 0.f, 0.f);
        for (int l = st; l < en; ++l) {
            const float* p = src + (size_t)l * H_;
            #pragma unroll
            for (int q = 0; q < 3; ++q) {
                float4 v = *(const float4*)(p + q * 4);
                s[q].x += v.x; s[q].y += v.y; s[q].z += v.z; s[q].w += v.w;
            }
        }
        _Float16* gp = pooledh + (size_t)bm * H_ + lane * 12;
        #pragma unroll
        for (int q = 0; q < 3; ++q) {
            half4t hv;
            hv[0] = (_Float16)(s[q].x * inv); hv[1] = (_Float16)(s[q].y * inv);
            hv[2] = (_Float16)(s[q].z * inv); hv[3] = (_Float16)(s[q].w * inv);
            *(half4t*)(gp + q * 4) = hv;
        }
        return;
    }
    // ---- prep part ----
    int idx = blockIdx.x * 256 + threadIdx.x;
    if (blockIdx.x == 0 && threadIdx.x < 160) {
        int n = threadIdx.x;
        bw[n] = (n < HID_) ? make_float2(b2[n], W3[n]) : make_float2(0.f, 0.f);
    }
    if (idx < 122880) {   // W1cs16: idx = k*160 + n
        int k = idx / 160, n = idx - k * 160;
        float v = (n < HID_) ? W1[(size_t)(2 * H_ + k) * HID_ + n] : 0.f;
        W1cs[((k >> 5) * 10 + (n >> 4)) * 512 +
             (((n & 15) | (((k >> 3) & 3) << 4)) << 3) + (k & 7)] = (_Float16)v;
        return;
    }
    idx -= 122880;
    if (idx < 25600) {    // W2s16: idx = k*160 + n
        int k = idx / 160, n = idx - k * 160;
        float v = (k < HID_ && n < HID_) ? W2[(size_t)k * HID_ + n] : 0.f;
        W2s[((k >> 5) * 10 + (n >> 4)) * 512 +
            (((n & 15) | (((k >> 3) & 3) << 4)) << 3) + (k & 7)] = (_Float16)v;
        return;
    }
    idx -= 25600;
    if (idx < 245760) {   // W1abs: idx = k*320 + n
        int k = idx / 320, n = idx - k * 320;
        float v = 0.f;
        if (n < HID_) v = W1[(size_t)k * HID_ + n];
        else if (n >= 160 && n < 160 + HID_) v = W1[(size_t)(H_ + k) * HID_ + (n - 160)];
        W1abs[(k >> 5) * 10240 + (n >> 4) * 512 +
              (((n & 15) | (((k >> 3) & 3) << 4)) << 3) + (k & 7)] = (_Float16)v;
    }
}

// ---------------------------------------------------------------------------
// Kernel 1: hi/hj projection (64 row-blocks x 4 n-quarters) [R9/R10-verified],
// zero-pads hiF cols 150..159 and hjT rows 150..159; zeroes loss scalar.
// ---------------------------------------------------------------------------
__global__ __launch_bounds__(64) void hihj_kernel(
    const _Float16* __restrict__ pooledh, const float* __restrict__ b1,
    const _Float16* __restrict__ W1abs,
    float* __restrict__ hiF, float* __restrict__ hjT, float* __restrict__ out)
{
    if (blockIdx.x == 0 && blockIdx.y == 0 && threadIdx.x == 0) *out = 0.f;
    const int rowblk = blockIdx.x;
    const int nq     = blockIdx.y;
    const int lane = threadIdx.x & 63;
    const int g = lane >> 4, l15 = lane & 15;
    floatx4 acc[5];
    #pragma unroll
    for (int u5 = 0; u5 < 5; ++u5) acc[u5] = (floatx4){0.f, 0.f, 0.f, 0.f};
    const _Float16* aB = pooledh + (size_t)(rowblk * 16 + l15) * H_ + g * 8;
    for (int kc = 0; kc < 24; ++kc) {
        half8 av = *(const half8*)(aB + kc * 32);
        #pragma unroll
        for (int u5 = 0; u5 < 5; ++u5) {
            const int u = nq * 5 + u5;
            half8 bv = *(const half8*)(W1abs + (size_t)((kc * 20 + u) * 64 + lane) * 8);
            acc[u5] = MFMA16(av, bv, acc[u5]);
        }
    }
    const int row0 = rowblk * 16 + g * 4;
    #pragma unroll
    for (int u5 = 0; u5 < 5; ++u5) {
        const int n = (nq * 5 + u5) * 16 + l15;
        if (n < HID_) {
            float b1v = b1[n];
            #pragma unroll
            for (int r = 0; r < 4; ++r)
                hiF[(size_t)(row0 + r) * 160 + n] = acc[u5][r] + b1v;
        } else if (n < 160) {
            #pragma unroll
            for (int r = 0; r < 4; ++r)
                hiF[(size_t)(row0 + r) * 160 + n] = 0.f;
        } else if (n < 160 + HID_) {
            *(float4*)&hjT[(size_t)(n - 160) * 1024 + row0] =
                make_float4(acc[u5][0], acc[u5][1], acc[u5][2], acc[u5][3]);
        } else {
            *(float4*)&hjT[(size_t)(n - 160) * 1024 + row0] =
                make_float4(0.f, 0.f, 0.f, 0.f);
        }
    }
}

// ---------------------------------------------------------------------------
// Kernel 2: fused pair MLP — R10 structure, occupancy-engineered.
// R10 post-mortem: VGPR 92 arch + 80 AGPR acc = 172/wave -> HW capped 2
// waves/SIMD; LDS 52.7 KB irrelevant. R11: (a) k32 weight dbuf (LDS 52.7 ->
// ~31 KB), (b) h1 per-m-tile (2 passes) to fit, (c) launch_bounds(256,3)
// with staging regs cut 20->12 -> 80+~85 = ~165 <= 170 -> 3 waves/SIMD
// (12 waves/CU, 1.5x R10), (d) pi rows staged in LDS too: the K-loop's
// compute path touches ONLY LDS (pif = 16-lane broadcast, free; pjL
// stride-70 measured 0 conflicts in R10).
// C/D 16x16: row=(lane>>4)*4+reg, col=lane&15 [hihj-verified].
// ---------------------------------------------------------------------------
__global__ __launch_bounds__(256, 3) void pair_mlp_kernel(
    const _Float16* __restrict__ pooledh,
    const float* __restrict__ hiF, const float* __restrict__ hjT,
    const _Float16* __restrict__ W1cs, const _Float16* __restrict__ W2s,
    const float2* __restrict__ bw, const float* __restrict__ b3,
    float* __restrict__ logits)
{
    // halves: sW dbuf [0,10240) (2 x 5120, k32 chunks); h1 (after stage1)
    // [0,10880) = 4 waves x 16 rows x 170; pjL [10880,15360) (2 x 32 x 70,
    // k64 chunks); piL [15360,15920) (2 x 4 x 70). Total 31840 B.
    __shared__ __align__(16) _Float16 smem[15920];
    _Float16* pjL = smem + 10880;
    _Float16* piL = smem + 15360;

    // ---- block decode (R9/R10-verified): 1152 = 4 b x 288 (4i x 32j) ----
    int q = blockIdx.x;
    const int b = q / 288;
    int r = q - b * 288;
    int h = 0;
    while (r >= 8 * (h + 1)) { r -= 8 * (h + 1); ++h; }
    const int gi = 8 * h + r / (h + 1);
    const int jt = r - (r / (h + 1)) * (h + 1);
    const int i0 = 4 * gi, j0 = 32 * jt;
    const int bm = b * M_;
    const int tid = threadIdx.x;
    const int w = tid >> 6, lane = tid & 63;
    const int g = lane >> 4, l15 = lane & 15;
    const int i = i0 + w;

    floatx4 acc[2][10];
    #pragma unroll
    for (int t = 0; t < 2; ++t)
        #pragma unroll
        for (int u = 0; u < 10; ++u) acc[t][u] = (floatx4){0.f, 0.f, 0.f, 0.f};

    const int prow = tid >> 3, pseg = tid & 7;     // pj staging: 32 rows x 8
    const _Float16* pjg = pooledh + (size_t)(bm + j0 + prow) * H_ + pseg * 8;
    const _Float16* pig = pooledh + (size_t)(bm + i0 + (tid >> 3)) * H_ + pseg * 8;

    // ---- prologue: weights k32-chunk 0 -> sW0; pj/pi k64-chunk 0 -> L ----
    {
        half8 s0 = *(const half8*)(W1cs + (size_t)tid * 8);
        half8 s1 = *(const half8*)(W1cs + (size_t)(tid + 256) * 8);
        half8 s2;
        if (tid < 128) s2 = *(const half8*)(W1cs + (size_t)(tid + 512) * 8);
        half8 pj0 = *(const half8*)pjg;
        half8 pi0;
        if (tid < 32) pi0 = *(const half8*)pig;
        *(half8*)&smem[tid * 8] = s0;
        *(half8*)&smem[(tid + 256) * 8] = s1;
        if (tid < 128) *(half8*)&smem[(tid + 512) * 8] = s2;
        *(half8*)&pjL[prow * 70 + pseg * 8] = pj0;
        if (tid < 32) *(half8*)&piL[(tid >> 3) * 70 + pseg * 8] = pi0;
    }
    __syncthreads();

    // ---- stage 1: 24 k32 chunks; weights dbuf k32, pj/pi dbuf k64 ----
    for (int cc = 0; cc < 24; ++cc) {
        const int wcur = cc & 1, pcur = (cc >> 1) & 1;
        const bool pfw = (cc < 23);
        const bool pfp = ((cc & 1) == 0) && (cc < 22);
        half8 s0, s1, s2, pjn, pin;
        if (pfw) {
            const _Float16* wg = W1cs + (size_t)(cc + 1) * 5120;
            s0 = *(const half8*)(wg + (size_t)tid * 8);
            s1 = *(const half8*)(wg + (size_t)(tid + 256) * 8);
            if (tid < 128) s2 = *(const half8*)(wg + (size_t)(tid + 512) * 8);
        }
        if (pfp) {
            pjn = *(const half8*)(pjg + ((cc >> 1) + 1) * 64);
            if (tid < 32) pin = *(const half8*)(pig + ((cc >> 1) + 1) * 64);
        }
        // compute on k32 chunk cc (LDS-only operands)
        half8 pif = *(const half8*)&piL[pcur * 280 + w * 70 + (cc & 1) * 32 + g * 8];
        half8 a0 = *(const half8*)&pjL[pcur * 2240 + l15 * 70 + (cc & 1) * 32 + g * 8] * pif;
        half8 a1 = *(const half8*)&pjL[pcur * 2240 + (16 + l15) * 70 + (cc & 1) * 32 + g * 8] * pif;
        const _Float16* wb = &smem[wcur * 5120 + lane * 8];
        #pragma unroll
        for (int u = 0; u < 10; ++u) {
            half8 bf = *(const half8*)(wb + u * 512);
            acc[0][u] = MFMA16(a0, bf, acc[0][u]);
            acc[1][u] = MFMA16(a1, bf, acc[1][u]);
        }
        if (pfw) {
            _Float16* d = &smem[(wcur ^ 1) * 5120];
            *(half8*)&d[tid * 8] = s0;
            *(half8*)&d[(tid + 256) * 8] = s1;
            if (tid < 128) *(half8*)&d[(tid + 512) * 8] = s2;
        }
        if (pfp) {
            *(half8*)&pjL[(pcur ^ 1) * 2240 + prow * 70 + pseg * 8] = pjn;
            if (tid < 32) *(half8*)&piL[(pcur ^ 1) * 280 + (tid >> 3) * 70 + pseg * 8] = pin;
        }
        __syncthreads();
    }

    // ---- per m-tile pass: epilogue1 -> LDS -> stage2 -> stage3 ----
    const float b3v = b3[0];
    _Float16* h1w = smem + (size_t)w * 2720;   // 16 rows x 170 per wave
    #pragma unroll
    for (int lt = 0; lt < 2; ++lt) {
        #pragma unroll
        for (int u = 0; u < 10; ++u) {
            const int n = u * 16 + l15;                // pads zeroed by hihj
            float hiv = hiF[(size_t)(bm + i) * 160 + n];
            float4 hjv = *(const float4*)&hjT[(size_t)n * 1024 + bm + j0 + lt * 16 + g * 4];
            h1w[(g * 4 + 0) * 170 + n] = (_Float16)fmaxf(acc[lt][u][0] + hiv + hjv.x, 0.f);
            h1w[(g * 4 + 1) * 170 + n] = (_Float16)fmaxf(acc[lt][u][1] + hiv + hjv.y, 0.f);
            h1w[(g * 4 + 2) * 170 + n] = (_Float16)fmaxf(acc[lt][u][2] + hiv + hjv.z, 0.f);
            h1w[(g * 4 + 3) * 170 + n] = (_Float16)fmaxf(acc[lt][u][3] + hiv + hjv.w, 0.f);
        }
        __syncthreads();

        floatx4 acc2[10];
        #pragma unroll
        for (int u = 0; u < 10; ++u) acc2[u] = (floatx4){0.f, 0.f, 0.f, 0.f};
        for (int kc2 = 0; kc2 < 5; ++kc2) {
            half8 a2 = *(const half8*)&h1w[l15 * 170 + kc2 * 32 + g * 8];
            const _Float16* w2b = W2s + (size_t)kc2 * 5120 + lane * 8;
            #pragma unroll
            for (int u = 0; u < 10; ++u) {
                half8 bf = *(const half8*)(w2b + u * 512);
                acc2[u] = MFMA16(a2, bf, acc2[u]);
            }
        }

        float sr[4] = {0.f, 0.f, 0.f, 0.f};
        #pragma unroll
        for (int u = 0; u < 10; ++u) {
            const int n2 = u * 16 + l15;
            float2 bwv = bw[n2];
            #pragma unroll
            for (int r2 = 0; r2 < 4; ++r2)
                sr[r2] += fmaxf(acc2[u][r2] + bwv.x, 0.f) * bwv.y;
        }
        #pragma unroll
        for (int r2 = 0; r2 < 4; ++r2) {
            float s = sr[r2];
            s += __shfl_xor(s, 1);
            s += __shfl_xor(s, 2);
            s += __shfl_xor(s, 4);
            s += __shfl_xor(s, 8);
            if (l15 == 0) {
                const int j = j0 + lt * 16 + g * 4 + r2;
                if (j < i)
                    logits[(size_t)(bm + i) * M_ + j] = s + b3v;
            }
        }
        __syncthreads();   // before lt=1 pass overwrites h1w
    }
}

// ---------------------------------------------------------------------------
// Kernel 3: per-row softmax over j<=i, clipped label-mass NLL, atomic sum.
// ---------------------------------------------------------------------------
__global__ __launch_bounds__(256) void loss_kernel(
    const float* __restrict__ logits, const float* __restrict__ labels,
    float* __restrict__ out)
{
    const int bm = blockIdx.x;
    const int i  = bm & (M_ - 1);
    const int j  = threadIdx.x;
    __shared__ float red[4];
    __shared__ float bcast;

    float val = (j < i) ? logits[(size_t)bm * M_ + j]
                        : ((j == i) ? 0.0f : -1e30f);

    float m = val;
    #pragma unroll
    for (int off = 32; off >= 1; off >>= 1) m = fmaxf(m, __shfl_down(m, off, 64));
    const int wave = j >> 6, lane = j & 63;
    if (lane == 0) red[wave] = m;
    __syncthreads();
    if (j == 0) bcast = fmaxf(fmaxf(red[0], red[1]), fmaxf(red[2], red[3]));
    __syncthreads();
    const float mm = bcast;

    float e = (j <= i) ? expf(val - mm) : 0.0f;
    float s = e;
    #pragma unroll
    for (int off = 32; off >= 1; off >>= 1) s += __shfl_down(s, off, 64);
    __syncthreads();
    if (lane == 0) red[wave] = s;
    __syncthreads();
    if (j == 0) bcast = red[0] + red[1] + red[2] + red[3];
    __syncthreads();
    const float ssum = bcast;

    float prob = (j <= i) ? (e / ssum) : -1000.0f;
    float lab = labels[(size_t)bm * M_ + j];
    float tv = prob * lab;
    tv = fminf(fmaxf(tv, 1e-8f), 1.0f - 1e-8f);
    float rs = tv;
    #pragma unroll
    for (int off = 32; off >= 1; off >>= 1) rs += __shfl_down(rs, off, 64);
    __syncthreads();
    if (lane == 0) red[wave] = rs;
    __syncthreads();
    if (j == 0) atomicAdd(out, -logf(red[0] + red[1] + red[2] + red[3]));
}

// ---------------------------------------------------------------------------
extern "C" void kernel_launch(void* const* d_in, const int* in_sizes, int n_in,
                              void* d_out, int out_size, void* d_ws, size_t ws_size,
                              hipStream_t stream)
{
    const float* hidden = (const float*)d_in[0];
    const int*   sutt   = (const int*)d_in[1];
    const int*   sstart = (const int*)d_in[2];
    const int*   send   = (const int*)d_in[3];
    const float* labels = (const float*)d_in[4];
    const float* W1     = (const float*)d_in[5];
    const float* b1     = (const float*)d_in[6];
    const float* W2     = (const float*)d_in[7];
    const float* b2     = (const float*)d_in[8];
    const float* W3     = (const float*)d_in[9];
    const float* b3     = (const float*)d_in[10];

    float* ws = (float*)d_ws;
    float*    hiF     = ws;                          // [1024][160]
    float*    hjT     = ws + 163840;                 // [160][1024]
    float*    logits  = ws + 327680;                 // 262144
    float2*   bw      = (float2*)(ws + 589824);      // 160 float2
    _Float16* pooledh = (_Float16*)(ws + 590144);    // 786432 f16
    _Float16* W1cs    = (_Float16*)(ws + 983360);    // 122880 f16 (16-pack)
    _Float16* W2s     = (_Float16*)(ws + 1106240);   // 25600 f16 (16-pack)
    _Float16* W1abs   = (_Float16*)(ws + 1119040);   // 245760 f16
    float* out = (float*)d_out;

    prep_pool_kernel<<<dim3(1796), 256, 0, stream>>>(
        W1, W2, b2, W3, hidden, sutt, sstart, send,
        W1cs, W2s, W1abs, bw, pooledh);
    hihj_kernel<<<dim3(64, 4), 64, 0, stream>>>(pooledh, b1, W1abs, hiF, hjT, out);
    pair_mlp_kernel<<<dim3(1152), 256, 0, stream>>>(pooledh, hiF, hjT,
                                                    W1cs, W2s, bw, b3, logits);
    loss_kernel<<<dim3(B_ * M_), 256, 0, stream>>>(logits, labels, out);
}

// Round 12
// 228.255 us; speedup vs baseline: 1.0824x; 1.0824x over previous
//
#include <hip/hip_runtime.h>
#include <hip/hip_bf16.h>

#define B_ 4
#define U_ 16
#define L_ 128
#define H_ 768
#define M_ 256
#define HID_ 150

typedef _Float16 half8 __attribute__((ext_vector_type(8)));
typedef _Float16 half4t __attribute__((ext_vector_type(4)));
typedef float floatx4 __attribute__((ext_vector_type(4)));

#define MFMA16(af, bf, acc) __builtin_amdgcn_mfma_f32_16x16x32_f16(af, bf, acc, 0, 0, 0)

// Direct global->LDS DMA, 16 B per lane; LDS dest = uniform base + lane*16.
#define GLDS(gaddr, laddr)                                                \
    __builtin_amdgcn_global_load_lds(                                     \
        (const __attribute__((address_space(1))) void*)(gaddr),           \
        (__attribute__((address_space(3))) void*)(laddr), 16, 0, 0)

// ---------------------------------------------------------------------------
// Kernel 0: fused prep (blocks 0..1539) + pool (blocks 1540..1795).
// 16x16 B-frag packing (HW-verified R6..R11): (k,n) ->
// ((k>>5)*T + (n>>4))*512 + (((n&15)|(((k>>3)&3)<<4))<<3) + (k&7).
// ---------------------------------------------------------------------------
__global__ __launch_bounds__(256) void prep_pool_kernel(
    const float* __restrict__ W1, const float* __restrict__ W2,
    const float* __restrict__ b2, const float* __restrict__ W3,
    const float* __restrict__ hidden, const int* __restrict__ sutt,
    const int* __restrict__ sstart, const int* __restrict__ send,
    _Float16* __restrict__ W1cs, _Float16* __restrict__ W2s,
    _Float16* __restrict__ W1abs, float2* __restrict__ bw,
    _Float16* __restrict__ pooledh)
{
    if (blockIdx.x >= 1540) {   // ---- pool part ----
        const int bm = (blockIdx.x - 1540) * 4 + (threadIdx.x >> 6);
        const int lane = threadIdx.x & 63;
        const int b  = bm >> 8;
        const int u  = sutt[bm];
        const int st = sstart[bm];
        const int en = send[bm];
        const float inv = 1.0f / (float)(en - st);
        const float* src = hidden + ((size_t)(b * U_ + u) * L_) * H_ + lane * 12;
        float4 s[3];
        #pragma unroll
        for (int q = 0; q < 3; ++q) s[q] = make_float4(0.f, 0.f, 0.f, 0.f);
        for (int l = st; l < en; ++l) {
            const float* p = src + (size_t)l * H_;
            #pragma unroll
            for (int q = 0; q < 3; ++q) {
                float4 v = *(const float4*)(p + q * 4);
                s[q].x += v.x; s[q].y += v.y; s[q].z += v.z; s[q].w += v.w;
            }
        }
        _Float16* gp = pooledh + (size_t)bm * H_ + lane * 12;
        #pragma unroll
        for (int q = 0; q < 3; ++q) {
            half4t hv;
            hv[0] = (_Float16)(s[q].x * inv); hv[1] = (_Float16)(s[q].y * inv);
            hv[2] = (_Float16)(s[q].z * inv); hv[3] = (_Float16)(s[q].w * inv);
            *(half4t*)(gp + q * 4) = hv;
        }
        return;
    }
    // ---- prep part ----
    int idx = blockIdx.x * 256 + threadIdx.x;
    if (blockIdx.x == 0 && threadIdx.x < 160) {
        int n = threadIdx.x;
        bw[n] = (n < HID_) ? make_float2(b2[n], W3[n]) : make_float2(0.f, 0.f);
    }
    if (idx < 122880) {   // W1cs16: idx = k*160 + n
        int k = idx / 160, n = idx - k * 160;
        float v = (n < HID_) ? W1[(size_t)(2 * H_ + k) * HID_ + n] : 0.f;
        W1cs[((k >> 5) * 10 + (n >> 4)) * 512 +
             (((n & 15) | (((k >> 3) & 3) << 4)) << 3) + (k & 7)] = (_Float16)v;
        return;
    }
    idx -= 122880;
    if (idx < 25600) {    // W2s16: idx = k*160 + n
        int k = idx / 160, n = idx - k * 160;
        float v = (k < HID_ && n < HID_) ? W2[(size_t)k * HID_ + n] : 0.f;
        W2s[((k >> 5) * 10 + (n >> 4)) * 512 +
            (((n & 15) | (((k >> 3) & 3) << 4)) << 3) + (k & 7)] = (_Float16)v;
        return;
    }
    idx -= 25600;
    if (idx < 245760) {   // W1abs: idx = k*320 + n
        int k = idx / 320, n = idx - k * 320;
        float v = 0.f;
        if (n < HID_) v = W1[(size_t)k * HID_ + n];
        else if (n >= 160 && n < 160 + HID_) v = W1[(size_t)(H_ + k) * HID_ + (n - 160)];
        W1abs[(k >> 5) * 10240 + (n >> 4) * 512 +
              (((n & 15) | (((k >> 3) & 3) << 4)) << 3) + (k & 7)] = (_Float16)v;
    }
}

// ---------------------------------------------------------------------------
// Kernel 1: hi/hj projection (64 row-blocks x 4 n-quarters) [R9/R10-verified],
// zero-pads hiF cols 150..159 and hjT rows 150..159; zeroes loss scalar.
// ---------------------------------------------------------------------------
__global__ __launch_bounds__(64) void hihj_kernel(
    const _Float16* __restrict__ pooledh, const float* __restrict__ b1,
    const _Float16* __restrict__ W1abs,
    float* __restrict__ hiF, float* __restrict__ hjT, float* __restrict__ out)
{
    if (blockIdx.x == 0 && blockIdx.y == 0 && threadIdx.x == 0) *out = 0.f;
    const int rowblk = blockIdx.x;
    const int nq     = blockIdx.y;
    const int lane = threadIdx.x & 63;
    const int g = lane >> 4, l15 = lane & 15;
    floatx4 acc[5];
    #pragma unroll
    for (int u5 = 0; u5 < 5; ++u5) acc[u5] = (floatx4){0.f, 0.f, 0.f, 0.f};
    const _Float16* aB = pooledh + (size_t)(rowblk * 16 + l15) * H_ + g * 8;
    for (int kc = 0; kc < 24; ++kc) {
        half8 av = *(const half8*)(aB + kc * 32);
        #pragma unroll
        for (int u5 = 0; u5 < 5; ++u5) {
            const int u = nq * 5 + u5;
            half8 bv = *(const half8*)(W1abs + (size_t)((kc * 20 + u) * 64 + lane) * 8);
            acc[u5] = MFMA16(av, bv, acc[u5]);
        }
    }
    const int row0 = rowblk * 16 + g * 4;
    #pragma unroll
    for (int u5 = 0; u5 < 5; ++u5) {
        const int n = (nq * 5 + u5) * 16 + l15;
        if (n < HID_) {
            float b1v = b1[n];
            #pragma unroll
            for (int r = 0; r < 4; ++r)
                hiF[(size_t)(row0 + r) * 160 + n] = acc[u5][r] + b1v;
        } else if (n < 160) {
            #pragma unroll
            for (int r = 0; r < 4; ++r)
                hiF[(size_t)(row0 + r) * 160 + n] = 0.f;
        } else if (n < 160 + HID_) {
            *(float4*)&hjT[(size_t)(n - 160) * 1024 + row0] =
                make_float4(acc[u5][0], acc[u5][1], acc[u5][2], acc[u5][3]);
        } else {
            *(float4*)&hjT[(size_t)(n - 160) * 1024 + row0] =
                make_float4(0.f, 0.f, 0.f, 0.f);
        }
    }
}

// ---------------------------------------------------------------------------
// Kernel 2: fused pair MLP — EXACT R10 structure (92 µs, absmax 0.0) with ONE
// change: weight staging via __builtin_amdgcn_global_load_lds (16B DMA).
// Removes ~40 VGPRs of staging regs + the vmcnt->ds_write serialization.
// No launch_bounds min-waves (R11 lesson: forcing 3/SIMD spills; let HW reach
// 3 waves/SIMD naturally from ~145 total regs). LDS 52.5 KB -> 3 blocks/CU.
// acc = 80 AGPR (R4/R6/R9 lesson: small accumulator sets only).
// C/D 16x16: row=(lane>>4)*4+reg, col=lane&15 [hihj-verified].
// ---------------------------------------------------------------------------
__global__ __launch_bounds__(256) void pair_mlp_kernel(
    const _Float16* __restrict__ pooledh,
    const float* __restrict__ hiF, const float* __restrict__ hjT,
    const _Float16* __restrict__ W1cs, const _Float16* __restrict__ W2s,
    const float2* __restrict__ bw, const float* __restrict__ b3,
    float* __restrict__ logits)
{
    // [0, 21760): union{ sW dbuf 2x10240 f16 | h1 128x170 f16 }
    // [21760, 26240): pjL dbuf 2 x 32x70 f16
    __shared__ __align__(16) _Float16 smem[26240];
    _Float16* pjL = smem + 21760;

    // ---- block decode (R9/R10-verified): 1152 = 4 b x 288 (4i x 32j) ----
    int q = blockIdx.x;
    const int b = q / 288;
    int r = q - b * 288;
    int h = 0;
    while (r >= 8 * (h + 1)) { r -= 8 * (h + 1); ++h; }
    const int gi = 8 * h + r / (h + 1);
    const int jt = r - (r / (h + 1)) * (h + 1);
    const int i0 = 4 * gi, j0 = 32 * jt;
    const int bm = b * M_;
    const int tid = threadIdx.x;
    const int w = tid >> 6, lane = tid & 63;
    const int g = lane >> 4, l15 = lane & 15;
    const int i = i0 + w;

    floatx4 acc[2][10];
    #pragma unroll
    for (int t = 0; t < 2; ++t)
        #pragma unroll
        for (int u = 0; u < 10; ++u) acc[t][u] = (floatx4){0.f, 0.f, 0.f, 0.f};

    const int prow = tid >> 3, pseg = tid & 7;     // pj staging coords
    const _Float16* pjg = pooledh + (size_t)(bm + j0 + prow) * H_ + pseg * 8;
    const _Float16* pip = pooledh + (size_t)(bm + i) * H_ + g * 8;

    // per-wave DMA addressing: wave w covers bytes [w*5120, w*5120+5120)
    const char* wgB = (const char*)W1cs + (size_t)w * 5120 + (size_t)lane * 16;
    char* ldB = (char*)smem + (size_t)w * 5120;

    // ---- prologue: stage chunk 0 (weights via DMA + pj via regs) ----
    {
        #pragma unroll
        for (int q2 = 0; q2 < 5; ++q2)
            GLDS(wgB + q2 * 1024, ldB + q2 * 1024);
        half8 pjst = *(const half8*)pjg;
        *(half8*)&pjL[prow * 70 + pseg * 8] = pjst;
    }
    __syncthreads();

    // ---- stage 1: 12 k64 chunks; weights DMA-dbuf, pj reg-dbuf ----
    for (int c = 0; c < 12; ++c) {
        const int cur = c & 1, nxt = cur ^ 1;
        half8 pjn;
        if (c < 11) {
            const char* wg = wgB + (size_t)(c + 1) * 20480;
            char* ld = (char*)smem + (size_t)nxt * 20480 + (size_t)w * 5120;
            #pragma unroll
            for (int q2 = 0; q2 < 5; ++q2)
                GLDS(wg + q2 * 1024, ld + q2 * 1024);
            pjn = *(const half8*)(pjg + (c + 1) * 64);
        }
        #pragma unroll
        for (int ks = 0; ks < 2; ++ks) {
            half8 pif = *(const half8*)(pip + c * 64 + ks * 32);
            half8 a0 = *(const half8*)&pjL[cur * 2240 + l15 * 70 + ks * 32 + g * 8] * pif;
            half8 a1 = *(const half8*)&pjL[cur * 2240 + (16 + l15) * 70 + ks * 32 + g * 8] * pif;
            const _Float16* wb = &smem[cur * 10240 + ks * 5120 + lane * 8];
            #pragma unroll
            for (int u = 0; u < 10; ++u) {
                half8 bf = *(const half8*)(wb + u * 512);
                acc[0][u] = MFMA16(a0, bf, acc[0][u]);
                acc[1][u] = MFMA16(a1, bf, acc[1][u]);
            }
        }
        if (c < 11)
            *(half8*)&pjL[nxt * 2240 + prow * 70 + pseg * 8] = pjn;
        __syncthreads();
    }

    // ---- epilogue 1: h1 = relu(acc + hi + hj) -> wave-private LDS rows ----
    _Float16* h1w = smem + (size_t)(w * 32) * 170;
    #pragma unroll
    for (int u = 0; u < 10; ++u) {
        const int n = u * 16 + l15;                // 0..159, pads are zeroed
        float hiv = hiF[(size_t)(bm + i) * 160 + n];
        #pragma unroll
        for (int t = 0; t < 2; ++t) {
            float4 hjv = *(const float4*)&hjT[(size_t)n * 1024 + bm + j0 + t * 16 + g * 4];
            h1w[(t * 16 + g * 4 + 0) * 170 + n] =
                (_Float16)fmaxf(acc[t][u][0] + hiv + hjv.x, 0.f);
            h1w[(t * 16 + g * 4 + 1) * 170 + n] =
                (_Float16)fmaxf(acc[t][u][1] + hiv + hjv.y, 0.f);
            h1w[(t * 16 + g * 4 + 2) * 170 + n] =
                (_Float16)fmaxf(acc[t][u][2] + hiv + hjv.z, 0.f);
            h1w[(t * 16 + g * 4 + 3) * 170 + n] =
                (_Float16)fmaxf(acc[t][u][3] + hiv + hjv.w, 0.f);
        }
    }
    __syncthreads();

    // ---- stage 2: h2pre = h1 @ W2 (A from LDS, B from hot L2, reuse x2) ----
    floatx4 acc2[2][10];
    #pragma unroll
    for (int t = 0; t < 2; ++t)
        #pragma unroll
        for (int u = 0; u < 10; ++u) acc2[t][u] = (floatx4){0.f, 0.f, 0.f, 0.f};

    for (int kc2 = 0; kc2 < 5; ++kc2) {
        half8 a20 = *(const half8*)&h1w[(0 * 16 + l15) * 170 + kc2 * 32 + g * 8];
        half8 a21 = *(const half8*)&h1w[(1 * 16 + l15) * 170 + kc2 * 32 + g * 8];
        const _Float16* w2b = W2s + (size_t)kc2 * 5120 + lane * 8;
        #pragma unroll
        for (int u = 0; u < 10; ++u) {
            half8 bf = *(const half8*)(w2b + u * 512);
            acc2[0][u] = MFMA16(a20, bf, acc2[0][u]);
            acc2[1][u] = MFMA16(a21, bf, acc2[1][u]);
        }
    }

    // ---- stage 3: s = relu(h2pre + b2) . W3 + b3 -> logits (j < i) ----
    const float b3v = b3[0];
    #pragma unroll
    for (int t = 0; t < 2; ++t) {
        float sr[4] = {0.f, 0.f, 0.f, 0.f};
        #pragma unroll
        for (int u = 0; u < 10; ++u) {
            const int n2 = u * 16 + l15;
            float2 bwv = bw[n2];
            #pragma unroll
            for (int r2 = 0; r2 < 4; ++r2)
                sr[r2] += fmaxf(acc2[t][u][r2] + bwv.x, 0.f) * bwv.y;
        }
        #pragma unroll
        for (int r2 = 0; r2 < 4; ++r2) {
            float s = sr[r2];
            s += __shfl_xor(s, 1);
            s += __shfl_xor(s, 2);
            s += __shfl_xor(s, 4);
            s += __shfl_xor(s, 8);
            if (l15 == 0) {
                const int j = j0 + t * 16 + g * 4 + r2;
                if (j < i)
                    logits[(size_t)(bm + i) * M_ + j] = s + b3v;
            }
        }
    }
}

// ---------------------------------------------------------------------------
// Kernel 3: per-row softmax over j<=i, clipped label-mass NLL, atomic sum.
// ---------------------------------------------------------------------------
__global__ __launch_bounds__(256) void loss_kernel(
    const float* __restrict__ logits, const float* __restrict__ labels,
    float* __restrict__ out)
{
    const int bm = blockIdx.x;
    const int i  = bm & (M_ - 1);
    const int j  = threadIdx.x;
    __shared__ float red[4];
    __shared__ float bcast;

    float val = (j < i) ? logits[(size_t)bm * M_ + j]
                        : ((j == i) ? 0.0f : -1e30f);

    float m = val;
    #pragma unroll
    for (int off = 32; off >= 1; off >>= 1) m = fmaxf(m, __shfl_down(m, off, 64));
    const int wave = j >> 6, lane = j & 63;
    if (lane == 0) red[wave] = m;
    __syncthreads();
    if (j == 0) bcast = fmaxf(fmaxf(red[0], red[1]), fmaxf(red[2], red[3]));
    __syncthreads();
    const float mm = bcast;

    float e = (j <= i) ? expf(val - mm) : 0.0f;
    float s = e;
    #pragma unroll
    for (int off = 32; off >= 1; off >>= 1) s += __shfl_down(s, off, 64);
    __syncthreads();
    if (lane == 0) red[wave] = s;
    __syncthreads();
    if (j == 0) bcast = red[0] + red[1] + red[2] + red[3];
    __syncthreads();
    const float ssum = bcast;

    float prob = (j <= i) ? (e / ssum) : -1000.0f;
    float lab = labels[(size_t)bm * M_ + j];
    float tv = prob * lab;
    tv = fminf(fmaxf(tv, 1e-8f), 1.0f - 1e-8f);
    float rs = tv;
    #pragma unroll
    for (int off = 32; off >= 1; off >>= 1) rs += __shfl_down(rs, off, 64);
    __syncthreads();
    if (lane == 0) red[wave] = rs;
    __syncthreads();
    if (j == 0) atomicAdd(out, -logf(red[0] + red[1] + red[2] + red[3]));
}

// ---------------------------------------------------------------------------
extern "C" void kernel_launch(void* const* d_in, const int* in_sizes, int n_in,
                              void* d_out, int out_size, void* d_ws, size_t ws_size,
                              hipStream_t stream)
{
    const float* hidden = (const float*)d_in[0];
    const int*   sutt   = (const int*)d_in[1];
    const int*   sstart = (const int*)d_in[2];
    const int*   send   = (const int*)d_in[3];
    const float* labels = (const float*)d_in[4];
    const float* W1     = (const float*)d_in[5];
    const float* b1     = (const float*)d_in[6];
    const float* W2     = (const float*)d_in[7];
    const float* b2     = (const float*)d_in[8];
    const float* W3     = (const float*)d_in[9];
    const float* b3     = (const float*)d_in[10];

    float* ws = (float*)d_ws;
    float*    hiF     = ws;                          // [1024][160]
    float*    hjT     = ws + 163840;                 // [160][1024]
    float*    logits  = ws + 327680;                 // 262144
    float2*   bw      = (float2*)(ws + 589824);      // 160 float2
    _Float16* pooledh = (_Float16*)(ws + 590144);    // 786432 f16
    _Float16* W1cs    = (_Float16*)(ws + 983360);    // 122880 f16 (16-pack)
    _Float16* W2s     = (_Float16*)(ws + 1106240);   // 25600 f16 (16-pack)
    _Float16* W1abs   = (_Float16*)(ws + 1119040);   // 245760 f16
    float* out = (float*)d_out;

    prep_pool_kernel<<<dim3(1796), 256, 0, stream>>>(
        W1, W2, b2, W3, hidden, sutt, sstart, send,
        W1cs, W2s, W1abs, bw, pooledh);
    hihj_kernel<<<dim3(64, 4), 64, 0, stream>>>(pooledh, b1, W1abs, hiF, hjT, out);
    pair_mlp_kernel<<<dim3(1152), 256, 0, stream>>>(pooledh, hiF, hjT,
                                                    W1cs, W2s, bw, b3, logits);
    loss_kernel<<<dim3(B_ * M_), 256, 0, stream>>>(logits, labels, out);
}